// Round 18
// baseline (224.537 us; speedup 1.0000x reference)
//
#include <hip/hip_runtime.h>
#include <stdint.h>

typedef __attribute__((ext_vector_type(8))) short short8;
typedef __attribute__((ext_vector_type(4))) float f32x4;
typedef unsigned short u16;

#define SBAR() do { __builtin_amdgcn_sched_barrier(0); \
                    __builtin_amdgcn_s_barrier(); \
                    __builtin_amdgcn_sched_barrier(0); } while (0)

__device__ __forceinline__ u16 f2bf(float f) {
  union { float f; uint32_t u; } v; v.f = f;
  return (u16)((v.u + 0x7FFFu + ((v.u >> 16) & 1u)) >> 16);
}
__device__ __forceinline__ float bf2f(u16 u) {
  union { uint32_t u; float f; } v; v.u = (uint32_t)u << 16; return v.f;
}

__device__ __forceinline__ void gl_lds16(const void* g, void* l) {
  __builtin_amdgcn_global_load_lds(
      (const __attribute__((address_space(1))) void*)g,
      (__attribute__((address_space(3))) void*)l, 16, 0, 0);
}

// -------- skinny GEMM: 64x128 tiles -> 256 blocks at M=2048,N=1024 ----------
__global__ __launch_bounds__(256) void gemm64_k(
    const u16* __restrict__ A, const u16* __restrict__ B,
    float* __restrict__ Cf, u16* __restrict__ Cb,
    const float* __restrict__ bias1,
    int M, int N, int K)
{
  __shared__ __align__(16) u16 As[64 * 32];    // 4 KB
  __shared__ __align__(16) u16 Bs[128 * 32];   // 8 KB
  const int t = threadIdx.x;
  const int lane = t & 63;
  const int w = t >> 6;
  const int wr = w >> 1, wc = w & 1;
  const int m0 = blockIdx.y * 64, n0 = blockIdx.x * 128;
  const int lr = lane & 15;
  const int lk = (lane >> 4) * 8;
  const int srow = t >> 2;
  const int scol = (t & 3) * 8;

  const u16* gA = A + (size_t)(m0 + srow) * K + scol;
  const u16* gB = B + (size_t)(n0 + srow) * K + scol;

  f32x4 acc[2][4] = {};

  for (int k0 = 0; k0 < K; k0 += 32) {
    gl_lds16(gA,                  As + t * 8);
    gl_lds16(gB,                  Bs + t * 8);
    gl_lds16(gB + (size_t)64 * K, Bs + 2048 + t * 8);
    gA += 32; gB += 32;
    __syncthreads();

    short8 a[2], b[4];
#pragma unroll
    for (int m = 0; m < 2; ++m)
      a[m] = *(const short8*)(As + (wr * 32 + m * 16 + lr) * 32 + lk);
#pragma unroll
    for (int n = 0; n < 4; ++n)
      b[n] = *(const short8*)(Bs + (wc * 64 + n * 16 + lr) * 32 + lk);
#pragma unroll
    for (int m = 0; m < 2; ++m)
#pragma unroll
      for (int n = 0; n < 4; ++n)
        acc[m][n] = __builtin_amdgcn_mfma_f32_16x16x32_bf16(a[m], b[n], acc[m][n], 0, 0, 0);
    __syncthreads();
  }

#pragma unroll
  for (int n = 0; n < 4; ++n) {
    int col = n0 + wc * 64 + n * 16 + lr;
    float bsum = bias1 ? bias1[col] : 0.f;
#pragma unroll
    for (int m = 0; m < 2; ++m) {
#pragma unroll
      for (int r = 0; r < 4; ++r) {
        int row = m0 + wr * 32 + m * 16 + (lane >> 4) * 4 + r;
        float vv = acc[m][n][r] + bsum;
        if (Cf) Cf[(size_t)row * N + col] = vv;
        if (Cb) Cb[(size_t)row * N + col] = f2bf(vv);
      }
    }
  }
}

// ---------------- gates GEMM: 256x256, BK=64, 8-wave, counted-vmcnt ----------
// R18: XCD m-band affinity — bid&7 (= XCD on MI355X round-robin dispatch)
// selects the m-band, so each XCD's 1MB A-panel stays L2-resident.
// Everything else verbatim R14/R17.
__global__ __launch_bounds__(512) void gates8_k(
    const u16* __restrict__ Xcat, const u16* __restrict__ Wcat,
    u16* __restrict__ gparts)
{
  __shared__ __align__(16) u16 lds[65536];     // 128 KB
  const int t = threadIdx.x;
  const int l = t & 63;
  const int w = t >> 6;
  const int wr = w >> 2, wc = w & 3;
  const int bid = blockIdx.x;
  // XCD-affine decode: m-band = bid&7 (one per XCD); rest covers n x khalf.
  const int m0 = (bid & 7) * 256;
  const int rest = bid >> 3;                   // 0..31
  const int n0 = (rest >> 1) * 256;
  const int khalf = rest & 1;
  const int lr = l & 15;
  const int l4 = l >> 4;

  const int sr = l >> 3;
  const int sc = ((l & 7) * 8) ^ (((((l >> 4) & 3) | ((w & 1) << 2))) << 3);

  const u16* Abase = Xcat + (size_t)m0 * 2048 + khalf * 1024 + sc;
  const u16* Bbase = Wcat + (size_t)n0 * 2048 + khalf * 1024 + sc;

  #define STAGE(buf, kt) do {                                                  \
    const int kof_ = (kt) * 64;                                                \
    _Pragma("unroll")                                                          \
    for (int hh = 0; hh < 2; ++hh)                                             \
      _Pragma("unroll")                                                        \
      for (int j = 0; j < 2; ++j) {                                            \
        int row_ = hh * 128 + (w + 8 * j) * 8 + sr;                            \
        char* dA = (char*)lds + (buf) * 65536 + hh * 16384 + (w + 8*j) * 1024 + l * 16; \
        char* dB = dA + 32768;                                                 \
        gl_lds16(Abase + (size_t)row_ * 2048 + kof_, dA);                      \
        gl_lds16(Bbase + (size_t)row_ * 2048 + kof_, dB);                      \
      }                                                                        \
  } while (0)

  auto LDA = [&](int buf, int mf, int s) -> short8 {
    int rr = mf * 16 + lr;
    int cb = (s * 64 + l4 * 16) ^ (((lr >> 1) & 7) << 4);
    return *(const short8*)((const char*)lds + buf * 65536 + wr * 16384 + rr * 128 + cb);
  };
  auto LDB = [&](int buf, int nf, int s) -> short8 {
    int rr = (wc & 1) * 64 + nf * 16 + lr;
    int cb = (s * 64 + l4 * 16) ^ (((lr >> 1) & 7) << 4);
    return *(const short8*)((const char*)lds + buf * 65536 + 32768 + (wc >> 1) * 16384 + rr * 128 + cb);
  };

  f32x4 acc[8][4] = {};

  STAGE(0, 0);
  STAGE(1, 1);
  asm volatile("s_waitcnt vmcnt(8)" ::: "memory");
  SBAR();

  for (int kt = 0; kt < 16; ++kt) {
    const int cur = kt & 1;
    short8 a0[4][2], a1[4][2], b[2][2];
#pragma unroll
    for (int i = 0; i < 4; ++i) { a0[i][0] = LDA(cur, i, 0); a0[i][1] = LDA(cur, i, 1); }
#pragma unroll
    for (int n = 0; n < 2; ++n) { b[n][0] = LDB(cur, n, 0); b[n][1] = LDB(cur, n, 1); }
    __builtin_amdgcn_s_setprio(1);
#pragma unroll
    for (int i = 0; i < 4; ++i)
#pragma unroll
      for (int n = 0; n < 2; ++n)
#pragma unroll
        for (int s = 0; s < 2; ++s)
          acc[i][n] = __builtin_amdgcn_mfma_f32_16x16x32_bf16(a0[i][s], b[n][s], acc[i][n], 0, 0, 0);
    __builtin_amdgcn_s_setprio(0);
#pragma unroll
    for (int i = 0; i < 4; ++i) { a1[i][0] = LDA(cur, 4 + i, 0); a1[i][1] = LDA(cur, 4 + i, 1); }
    __builtin_amdgcn_s_setprio(1);
#pragma unroll
    for (int i = 0; i < 4; ++i)
#pragma unroll
      for (int n = 0; n < 2; ++n)
#pragma unroll
        for (int s = 0; s < 2; ++s)
          acc[4 + i][n] = __builtin_amdgcn_mfma_f32_16x16x32_bf16(a1[i][s], b[n][s], acc[4 + i][n], 0, 0, 0);
    __builtin_amdgcn_s_setprio(0);
#pragma unroll
    for (int n = 0; n < 2; ++n) { b[n][0] = LDB(cur, 2 + n, 0); b[n][1] = LDB(cur, 2 + n, 1); }
    __builtin_amdgcn_s_setprio(1);
#pragma unroll
    for (int i = 0; i < 4; ++i)
#pragma unroll
      for (int n = 0; n < 2; ++n)
#pragma unroll
        for (int s = 0; s < 2; ++s)
          acc[4 + i][2 + n] = __builtin_amdgcn_mfma_f32_16x16x32_bf16(a1[i][s], b[n][s], acc[4 + i][2 + n], 0, 0, 0);
#pragma unroll
    for (int i = 0; i < 4; ++i)
#pragma unroll
      for (int n = 0; n < 2; ++n)
#pragma unroll
        for (int s = 0; s < 2; ++s)
          acc[i][2 + n] = __builtin_amdgcn_mfma_f32_16x16x32_bf16(a0[i][s], b[n][s], acc[i][2 + n], 0, 0, 0);
    __builtin_amdgcn_s_setprio(0);

    SBAR();
    if (kt + 2 < 16) {
      STAGE(cur, kt + 2);
      asm volatile("s_waitcnt vmcnt(8)" ::: "memory");
    } else {
      asm volatile("s_waitcnt vmcnt(0)" ::: "memory");
    }
    SBAR();
  }
  #undef STAGE

  u16* out = gparts + (size_t)khalf * 2048 * 4096;
#pragma unroll
  for (int nf = 0; nf < 4; ++nf) {
    int col = n0 + wc * 64 + nf * 16 + lr;
#pragma unroll
    for (int mf = 0; mf < 8; ++mf)
#pragma unroll
      for (int r = 0; r < 4; ++r) {
        int row = m0 + wr * 128 + mf * 16 + l4 * 4 + r;
        out[(size_t)row * 4096 + col] = f2bf(acc[mf][nf][r]);
      }
  }
}

// ---------------- prepQ: Wq/Wk transposes only (512 blocks, short head) -----
__global__ __launch_bounds__(256) void prepQ_k(
    const float* __restrict__ Wq, const float* __restrict__ Wk,
    u16* __restrict__ wqtb, u16* __restrict__ wktb)
{
  __shared__ u16 tile[64][65];
  int blk = blockIdx.x;
  int t = threadIdx.x;
  const float* src; u16* dst; int tblk;
  if (blk < 256) { src = Wq; dst = wqtb; tblk = blk; }
  else           { src = Wk; dst = wktb; tblk = blk - 256; }
  int tr = (tblk >> 4) * 64, tc = (tblk & 15) * 64;
  int tx = t & 63;
  int ty = (t >> 6) * 16;
#pragma unroll
  for (int i = 0; i < 16; ++i)
    tile[ty + i][tx] = f2bf(src[(size_t)(tr + ty + i) * 1024 + tc + tx]);
  __syncthreads();
#pragma unroll
  for (int i = 0; i < 16; ++i)
    dst[(size_t)(tc + ty + i) * 1024 + tr + tx] = tile[tx][ty + i];
}

// ---------------- prepRG: G gemm + bqwk + ALL packs (incl. query) -----------
__global__ __launch_bounds__(256) void prepRG_k(
    const float* __restrict__ pose, const float* __restrict__ h,
    const float* __restrict__ W_ih, const float* __restrict__ W_hh,
    const float* __restrict__ Wv, const float* __restrict__ query,
    const u16* __restrict__ WkTb, const u16* __restrict__ WqTb,
    const float* __restrict__ bq, const float* __restrict__ Wk,
    u16* __restrict__ xcat, u16* __restrict__ wcat, u16* __restrict__ wvb,
    u16* __restrict__ qry, u16* __restrict__ Gb, float* __restrict__ qkb)
{
  __shared__ __align__(16) u16 As[128 * 32];
  __shared__ __align__(16) u16 Bs[128 * 32];
  const int blk = blockIdx.x;
  const int t = threadIdx.x;
  if (blk < 64) {
    const int lane = t & 63;
    const int w = t >> 6;
    const int wr = w >> 1, wc = w & 1;
    const int m0 = (blk >> 3) * 128, n0 = (blk & 7) * 128;
    const int lr = lane & 15;
    const int lk = (lane >> 4) * 8;
    const int srow = t >> 2;
    const int scol = (t & 3) * 8;
    const u16* gA = WkTb + (size_t)(m0 + srow) * 1024 + scol;
    const u16* gB = WqTb + (size_t)(n0 + srow) * 1024 + scol;
    f32x4 acc[4][4] = {};
    for (int k0 = 0; k0 < 1024; k0 += 32) {
      gl_lds16(gA,                     As + t * 8);
      gl_lds16(gA + (size_t)64 * 1024, As + 2048 + t * 8);
      gl_lds16(gB,                     Bs + t * 8);
      gl_lds16(gB + (size_t)64 * 1024, Bs + 2048 + t * 8);
      gA += 32; gB += 32;
      __syncthreads();
      short8 a[4], b[4];
#pragma unroll
      for (int m = 0; m < 4; ++m)
        a[m] = *(const short8*)(As + (wr * 64 + m * 16 + lr) * 32 + lk);
#pragma unroll
      for (int n = 0; n < 4; ++n)
        b[n] = *(const short8*)(Bs + (wc * 64 + n * 16 + lr) * 32 + lk);
#pragma unroll
      for (int m = 0; m < 4; ++m)
#pragma unroll
        for (int n = 0; n < 4; ++n)
          acc[m][n] = __builtin_amdgcn_mfma_f32_16x16x32_bf16(a[m], b[n], acc[m][n], 0, 0, 0);
      __syncthreads();
    }
#pragma unroll
    for (int n = 0; n < 4; ++n) {
      int col = n0 + wc * 64 + n * 16 + lr;
#pragma unroll
      for (int m = 0; m < 4; ++m)
#pragma unroll
        for (int r = 0; r < 4; ++r) {
          int row = m0 + wr * 64 + m * 16 + (lane >> 4) * 4 + r;
          Gb[(size_t)row * 1024 + col] = f2bf(acc[m][n][r]);
        }
    }
    return;
  }
  if (blk < 68) {
    int n = (blk - 64) * 256 + t;
    float s0 = 0.f, s1 = 0.f;
    for (int j = 0; j < 1024; j += 2) {
      s0 += bq[j]     * Wk[(size_t)j * 1024 + n];
      s1 += bq[j + 1] * Wk[(size_t)(j + 1) * 1024 + n];
    }
    qkb[n] = s0 + s1;
    return;
  }
  int b2 = blk - 68;
  const float* src; u16* dst; int ostride, ooff, base;
  if (b2 < 2048)        { src = pose;  dst = xcat; ostride = 2048; ooff = 0;    base = 0; }
  else if (b2 < 4096)   { src = h;     dst = xcat; ostride = 2048; ooff = 1024; base = 2048; }
  else if (b2 < 8192)   { src = W_ih;  dst = wcat; ostride = 2048; ooff = 0;    base = 4096; }
  else if (b2 < 12288)  { src = W_hh;  dst = wcat; ostride = 2048; ooff = 1024; base = 8192; }
  else if (b2 < 13312)  { src = Wv;    dst = wvb;  ostride = 1024; ooff = 0;    base = 12288; }
  else                  { src = query; dst = qry;  ostride = 1024; ooff = 0;    base = 13312; }
  int r = b2 - base;
  int cc = t * 4;
  float4 v = *(const float4*)(src + (size_t)r * 1024 + cc);
  ushort4 o; o.x = f2bf(v.x); o.y = f2bf(v.y); o.z = f2bf(v.z); o.w = f2bf(v.w);
  *(ushort4*)(dst + (size_t)r * ostride + ooff + cc) = o;
}

// ---- fused attention + LSTM finish (verbatim R17) --------------------------
__global__ __launch_bounds__(256) void attnfin_k(
    const float* __restrict__ Qk, const float* __restrict__ mem,
    const u16* __restrict__ gparts, const float* __restrict__ c,
    const float* __restrict__ b_ih, const float* __restrict__ b_hh,
    float* __restrict__ out_h, float* __restrict__ out_c,
    u16* __restrict__ ctxb)
{
  const int t = threadIdx.x;
  const int lane = t & 63;
  const int b = blockIdx.x * 4 + (t >> 6);
  const float* q = Qk + (size_t)b * 1024;
  f32x4 qv[4];
#pragma unroll
  for (int i = 0; i < 4; ++i)
    qv[i] = *(const f32x4*)(q + (i * 64 + lane) * 4);
  const float* mb = mem + (size_t)b * 65536;

  float m_run = -3e38f, l = 0.f;
  f32x4 cx[4] = {};

  for (int qd = 0; qd < 15; ++qd) {
    const float* r0 = mb + (size_t)(1 + qd * 4) * 1024;
    f32x4 rv[4][4];
    float s[4] = {0.f, 0.f, 0.f, 0.f};
#pragma unroll
    for (int rr = 0; rr < 4; ++rr)
#pragma unroll
      for (int i = 0; i < 4; ++i) {
        rv[rr][i] = __builtin_nontemporal_load(
            (const f32x4*)(r0 + rr * 1024 + (i * 64 + lane) * 4));
        s[rr] += rv[rr][i][0] * qv[i][0] + rv[rr][i][1] * qv[i][1] +
                 rv[rr][i][2] * qv[i][2] + rv[rr][i][3] * qv[i][3];
      }
#pragma unroll
    for (int rr = 0; rr < 4; ++rr) {
#pragma unroll
      for (int off = 32; off; off >>= 1) s[rr] += __shfl_xor(s[rr], off);
      s[rr] *= 0.03125f;
    }
#pragma unroll
    for (int rr = 0; rr < 4; ++rr) {
      if (s[rr] <= m_run + 8.f) {
        float e = __expf(s[rr] - m_run);
        l += e;
#pragma unroll
        for (int i = 0; i < 4; ++i) cx[i] += rv[rr][i] * e;
      } else {
        float sc = __expf(m_run - s[rr]);
        m_run = s[rr];
        l = l * sc + 1.f;
#pragma unroll
        for (int i = 0; i < 4; ++i) cx[i] = cx[i] * sc + rv[rr][i];
      }
    }
  }
  for (int r = 61; r <= 63; ++r) {
    const float* row = mb + (size_t)r * 1024;
    f32x4 rv[4];
    float s = 0.f;
#pragma unroll
    for (int i = 0; i < 4; ++i) {
      rv[i] = __builtin_nontemporal_load(
          (const f32x4*)(row + (i * 64 + lane) * 4));
      s += rv[i][0] * qv[i][0] + rv[i][1] * qv[i][1] +
           rv[i][2] * qv[i][2] + rv[i][3] * qv[i][3];
    }
#pragma unroll
    for (int off = 32; off; off >>= 1) s += __shfl_xor(s, off);
    s *= 0.03125f;
    if (s <= m_run + 8.f) {
      float e = __expf(s - m_run);
      l += e;
#pragma unroll
      for (int i = 0; i < 4; ++i) cx[i] += rv[i] * e;
    } else {
      float sc = __expf(m_run - s);
      m_run = s;
      l = l * sc + 1.f;
#pragma unroll
      for (int i = 0; i < 4; ++i) cx[i] = cx[i] * sc + rv[i];
    }
  }

  const u16* g0 = gparts + (size_t)b * 4096;
  const u16* g1 = g0 + (size_t)2048 * 4096;
  f32x4 hn[4];
  float s_last = 0.f;
#pragma unroll
  for (int i = 0; i < 4; ++i) {
    const int base = (i * 64 + lane) * 4;
    float gsum[4][4];
#pragma unroll
    for (int gi = 0; gi < 4; ++gi) {
      ushort4 a = *(const ushort4*)(g0 + gi * 1024 + base);
      ushort4 bb = *(const ushort4*)(g1 + gi * 1024 + base);
      float4 bi = *(const float4*)(b_ih + gi * 1024 + base);
      float4 bh = *(const float4*)(b_hh + gi * 1024 + base);
      gsum[gi][0] = bf2f(a.x) + bf2f(bb.x) + bi.x + bh.x;
      gsum[gi][1] = bf2f(a.y) + bf2f(bb.y) + bi.y + bh.y;
      gsum[gi][2] = bf2f(a.z) + bf2f(bb.z) + bi.z + bh.z;
      gsum[gi][3] = bf2f(a.w) + bf2f(bb.w) + bi.w + bh.w;
    }
    float4 cv = *(const float4*)(c + (size_t)b * 1024 + base);
    float cvs[4] = {cv.x, cv.y, cv.z, cv.w};
    f32x4 cnv;
#pragma unroll
    for (int j = 0; j < 4; ++j) {
      float si = 1.f / (1.f + __expf(-gsum[0][j]));
      float sf = 1.f / (1.f + __expf(-gsum[1][j]));
      float so = 1.f / (1.f + __expf(-gsum[3][j]));
      float tg = 2.f / (1.f + __expf(-2.f * gsum[2][j])) - 1.f;
      float cn = sf * cvs[j] + si * tg;
      float tc2 = 2.f / (1.f + __expf(-2.f * cn)) - 1.f;
      cnv[j] = cn;
      hn[i][j] = so * tc2;
    }
    *(f32x4*)(out_c + (size_t)b * 1024 + base) = cnv;
    *(f32x4*)(out_h + (size_t)b * 1024 + base) = hn[i];
    s_last += qv[i][0] * hn[i][0] + qv[i][1] * hn[i][1] +
              qv[i][2] * hn[i][2] + qv[i][3] * hn[i][3];
  }
#pragma unroll
  for (int off = 32; off; off >>= 1) s_last += __shfl_xor(s_last, off);
  s_last *= 0.03125f;

  if (s_last <= m_run + 8.f) {
    float e = __expf(s_last - m_run);
    l += e;
#pragma unroll
    for (int i = 0; i < 4; ++i) cx[i] += hn[i] * e;
  } else {
    float sc = __expf(m_run - s_last);
    l = l * sc + 1.f;
#pragma unroll
    for (int i = 0; i < 4; ++i) cx[i] = cx[i] * sc + hn[i];
  }
  float inv = 1.f / l;
#pragma unroll
  for (int i = 0; i < 4; ++i) {
    ushort4 o;
    o.x = f2bf(cx[i][0] * inv); o.y = f2bf(cx[i][1] * inv);
    o.z = f2bf(cx[i][2] * inv); o.w = f2bf(cx[i][3] * inv);
    *(ushort4*)(ctxb + (size_t)b * 1024 + (i * 64 + lane) * 4) = o;
  }
}

extern "C" void kernel_launch(void* const* d_in, const int* in_sizes, int n_in,
                              void* d_out, int out_size, void* d_ws, size_t ws_size,
                              hipStream_t stream) {
  const int Bb = 2048, Hh = 1024;
  const float* pose  = (const float*)d_in[0];
  const float* query = (const float*)d_in[1];
  const float* h     = (const float*)d_in[2];
  const float* c     = (const float*)d_in[3];
  const float* mem   = (const float*)d_in[4];
  const float* W_ih  = (const float*)d_in[5];
  const float* W_hh  = (const float*)d_in[6];
  const float* b_ih  = (const float*)d_in[7];
  const float* b_hh  = (const float*)d_in[8];
  const float* Wq    = (const float*)d_in[9];
  const float* bq    = (const float*)d_in[10];
  const float* Wk    = (const float*)d_in[11];
  // d_in[12] = bk: m-independent score shift, cancels in softmax
  const float* Wv    = (const float*)d_in[13];
  const float* bv    = (const float*)d_in[14];

  float* out_att = (float*)d_out;
  float* out_h   = out_att + (size_t)Bb * Hh;
  float* out_c   = out_h + (size_t)Bb * Hh;

  char* wp = (char*)d_ws;
  auto alloc = [&](size_t bytes) {
    char* p = wp; wp += (bytes + 255) & ~(size_t)255; return p;
  };
  u16*   Xcat  = (u16*)alloc((size_t)2048 * 2048 * 2);   // 8 MB
  u16*   Wcat  = (u16*)alloc((size_t)4096 * 2048 * 2);   // 16 MB
  u16*   Qryb  = (u16*)alloc((size_t)2048 * 1024 * 2);   // 4 MB
  u16*   WqTb  = (u16*)alloc((size_t)1024 * 1024 * 2);   // 2 MB
  u16*   WkTb  = (u16*)alloc((size_t)1024 * 1024 * 2);   // 2 MB
  u16*   Gb    = (u16*)alloc((size_t)1024 * 1024 * 2);   // 2 MB
  u16*   Wvb   = (u16*)alloc((size_t)1024 * 1024 * 2);   // 2 MB
  u16*   gparts= (u16*)alloc((size_t)2 * 2048 * 4096 * 2); // 32 MB
  float* qkb   = (float*)alloc((size_t)1024 * 4);
  float* Qk    = (float*)alloc((size_t)2048 * 1024 * 4); // 8 MB
  u16*   ctxb  = (u16*)alloc((size_t)2048 * 1024 * 2);   // 4 MB

  // 1. prepQ: Wq/Wk transposes (short serial head feeding G)
  prepQ_k<<<512, 256, 0, stream>>>(Wq, Wk, WqTb, WkTb);

  // 2. prepRG: G gemm (64) + bqwk (4) + all packs incl. query (15360)
  prepRG_k<<<15428, 256, 0, stream>>>(pose, h, W_ih, W_hh, Wv, query,
                                      WkTb, WqTb, bq, Wk,
                                      Xcat, Wcat, Wvb, Qryb, Gb, qkb);

  // 3. Qk = query @ G^T + bq@Wk  (64x128 tiles -> 256 blocks)
  gemm64_k<<<dim3(8, 32), 256, 0, stream>>>(
      Qryb, Gb, Qk, nullptr, qkb, 2048, 1024, 1024);

  // 4. gates: 256^2 8-wave counted-vmcnt kernel, XCD m-band affinity
  gates8_k<<<256, 512, 0, stream>>>(Xcat, Wcat, gparts);

  // 5. fused attention (rows 1..63) + LSTM + h_new fold + ctx
  attnfin_k<<<512, 256, 0, stream>>>(Qk, mem, gparts, c, b_ih, b_hh,
                                     out_h, out_c, ctxb);

  // 6. attended = ctx @ Wv^T + bv  (64x128 tiles -> 256 blocks)
  gemm64_k<<<dim3(8, 32), 256, 0, stream>>>(
      ctxb, Wvb, out_att, nullptr, bv, 2048, 1024, 1024);
}